// Round 10
// baseline (55.915 us; speedup 1.0000x reference)
//
#include <hip/hip_runtime.h>

#define F 32

typedef float v4f __attribute__((ext_vector_type(4)));   // clang-native: nt-store OK

// ---- bf16 helpers (manual, RNE) -------------------------------------------
__device__ __forceinline__ unsigned int f2bf_rne(float f) {
    unsigned int u = __float_as_uint(f);
    return (u + 0x7fffu + ((u >> 16) & 1u)) >> 16;          // bf16 bits in low 16
}
__device__ __forceinline__ float bf_lo(unsigned int u) { return __uint_as_float(u << 16); }
__device__ __forceinline__ float bf_hi(unsigned int u) { return __uint_as_float(u & 0xffff0000u); }

// ---------------------------------------------------------------------------
// Prep (fused, 2 block ranges) — unchanged from R9 (fast).
//  [0, gxw):   y = x @ W -> bf16-pair packed [n][16 uints] (6.4 MB).
//  [gxw, ...): CSR row_ptr boundary fill from sorted COO rows.
// ---------------------------------------------------------------------------
__global__ void prep_kernel(const float* __restrict__ x, const float* __restrict__ w,
                            uint4* __restrict__ y4,
                            const int* __restrict__ rows,
                            int* __restrict__ row_ptr,
                            int n_nodes, int n_edges, int gxw) {
    int b = blockIdx.x;
    if (b < gxw) {
        int n = b * blockDim.x + threadIdx.x;
        if (n >= n_nodes) return;
        const float4* xp = (const float4*)(x + (size_t)n * F);
        float xr[F];
#pragma unroll
        for (int j = 0; j < 8; ++j) {
            float4 t = xp[j];
            xr[4*j+0] = t.x; xr[4*j+1] = t.y; xr[4*j+2] = t.z; xr[4*j+3] = t.w;
        }
        float acc[F];
#pragma unroll
        for (int f = 0; f < F; ++f) acc[f] = 0.f;
#pragma unroll
        for (int k = 0; k < F; ++k) {
            float xk = xr[k];
#pragma unroll
            for (int f = 0; f < F; ++f)
                acc[f] = fmaf(xk, w[k * F + f], acc[f]);   // w uniform -> s_load
        }
        unsigned int op[16];
#pragma unroll
        for (int k = 0; k < 16; ++k)
            op[k] = f2bf_rne(acc[2*k]) | (f2bf_rne(acc[2*k+1]) << 16);
#pragma unroll
        for (int j = 0; j < 4; ++j)
            y4[(size_t)n * 4 + j] = make_uint4(op[4*j], op[4*j+1], op[4*j+2], op[4*j+3]);
    } else {
        int e = (b - gxw) * blockDim.x + threadIdx.x;
        if (e > n_edges) return;
        int prev = (e == 0) ? -1 : rows[e - 1];
        int cur  = (e == n_edges) ? n_nodes : rows[e];
        for (int r = prev + 1; r <= cur; ++r) row_ptr[r] = e;   // covers [0, N]
    }
}

// ---------------------------------------------------------------------------
// SpMM v10 = v6's gather shape minus its overheads (R9 post-mortem).
// 4-lane group per node; lane l holds 16 B of the 64 B bf16 y-row
// (features 8l..8l+7). Per wave: 16 groups; per 8-edge batch-iter:
//   - metadata DIRECT from cols/vals (no pk pack pass, no q15 decode —
//     v6's regression source). 4 lanes/group share one address.
//   - 8 uint4 gathers back-to-back: 16 lines/inst x 8 = 128 cache lines
//     outstanding per wave (2x v9) -> max Little's-law MLP.
//   - per-edge issue cost ~2.7 cy (v9: ~6); TA addr cost 1 cy/edge (v9: 4).
// OOB edges clamp to e0 (valid whenever loop entered), val=0.
// ---------------------------------------------------------------------------
__global__ void spmm_kernel(const uint4* __restrict__ y4,
                            const int* __restrict__ cols,
                            const float* __restrict__ vals,
                            const int* __restrict__ row_ptr,
                            v4f* __restrict__ out4, int n_nodes) {
    int gid = blockIdx.x * blockDim.x + threadIdx.x;
    int n = gid >> 2;
    int l = gid & 3;
    if (n >= n_nodes) return;

    int e0 = row_ptr[n];
    int e1 = row_ptr[n + 1];
    float a0 = 0.f, a1 = 0.f, a2 = 0.f, a3 = 0.f,
          a4 = 0.f, a5 = 0.f, a6 = 0.f, a7 = 0.f;

    for (int base = e0; base < e1; base += 8) {
        int   c[8]; float v[8];
#pragma unroll
        for (int j = 0; j < 8; ++j) {
            int idx = base + j;
            bool ok = idx < e1;
            int idx2 = ok ? idx : e0;
            c[j] = cols[idx2];                       // group-uniform address
            v[j] = ok ? vals[idx2] : 0.f;
        }
        uint4 u[8];
#pragma unroll
        for (int j = 0; j < 8; ++j)
            u[j] = y4[(size_t)c[j] * 4 + l];         // 16 lines/inst, 8 in flight
#pragma unroll
        for (int j = 0; j < 8; ++j) {
            a0 += bf_lo(u[j].x) * v[j];  a1 += bf_hi(u[j].x) * v[j];
            a2 += bf_lo(u[j].y) * v[j];  a3 += bf_hi(u[j].y) * v[j];
            a4 += bf_lo(u[j].z) * v[j];  a5 += bf_hi(u[j].z) * v[j];
            a6 += bf_lo(u[j].w) * v[j];  a7 += bf_hi(u[j].w) * v[j];
        }
    }
    v4f* op = out4 + (size_t)n * 8 + l * 2;          // lane l -> features 8l..8l+7
    v4f o0; o0[0] = a0; o0[1] = a1; o0[2] = a2; o0[3] = a3;
    v4f o1; o1[0] = a4; o1[1] = a5; o1[2] = a6; o1[3] = a7;
    __builtin_nontemporal_store(o0, &op[0]);
    __builtin_nontemporal_store(o1, &op[1]);
}

// ---------------------------------------------------------------------------
extern "C" void kernel_launch(void* const* d_in, const int* in_sizes, int n_in,
                              void* d_out, int out_size, void* d_ws, size_t ws_size,
                              hipStream_t stream) {
    const float* x    = (const float*)d_in[0];
    const int*   rows = (const int*)d_in[1];
    const int*   cols = (const int*)d_in[2];
    const float* vals = (const float*)d_in[3];
    const float* w    = (const float*)d_in[4];

    int n_nodes = in_sizes[0] / F;   // 100000
    int n_edges = in_sizes[1];       // 1600000

    // ws: y [n_nodes * 4 uint4 = 6.4 MB] | row_ptr [N+1]
    uint4* y4      = (uint4*)d_ws;
    int*   row_ptr = (int*)((char*)d_ws + (size_t)n_nodes * 16 * sizeof(unsigned int));

    int gxw = (n_nodes + 255) / 256;
    int gpe = (n_edges + 1 + 255) / 256;
    prep_kernel<<<gxw + gpe, 256, 0, stream>>>(x, w, y4, rows, row_ptr,
                                               n_nodes, n_edges, gxw);

    int grid_spmm = (n_nodes * 4 + 255) / 256;
    spmm_kernel<<<grid_spmm, 256, 0, stream>>>(y4, cols, vals, row_ptr,
                                               (v4f*)d_out, n_nodes);
}